// Round 2
// baseline (1477.362 us; speedup 1.0000x reference)
//
#include <hip/hip_runtime.h>

// CumSumLoop: x [B=128, T=8192, C=64] fp32, running cumsum over T, + s_init[C].
//
// Single-pass chained scan (decoupled aggregates + ticket ordering):
//   - one 256-thread block per 32 KB chunk (L=128 t-steps), x held in registers
//   - per-chunk two-level scan: 8-deep serial per thread, 16-wide Hillis-Steele in LDS
//   - chunk aggregate published (release flag, agent scope) BEFORE lookback
//   - lookback = flat sum of all predecessor aggregates (<=63 x 256B, L2-hot)
//   - atomic ticket: lower tickets are resident-or-retired -> predecessors always publish
//   - HARDENING: bounded spin; on timeout a lane recomputes the predecessor
//     aggregate straight from x (32 KB) -> kernel can never hang, only slow down.
// x is fetched from HBM exactly once (vs twice in the 2-pass version): 805 -> 545 MB.

typedef float f4 __attribute__((ext_vector_type(4)));

#define B      128
#define T      8192
#define NC     64            // chunks along T per batch row
#define L      (T / NC)      // 128 t-steps per chunk
#define ROW4   16            // float4 per t-row (C=64)
#define CH4    (L * ROW4)    // 2048 float4 per chunk
#define NCHUNK (B * NC)      // 8192 chunks total
#define VPT    (L / 16)      // 8 t-rows per thread (256 thr = 16 s-groups x 16 g)

// workspace layout (bytes):
//   [0]      u32 ticket counter
//   [256]    u32 flags[NCHUNK]                (32 KB)
//   [33024]  f4  agg[NCHUNK][16]              (2 MB)
#define FLAGS_OFF_U32 64
#define AGG_OFF_U32   8256
#define WS_NEED       (33024u + (size_t)NCHUNK * 16 * sizeof(f4))

// ---- init: zero ticket + flags each launch (graph-replay safe, stream-ordered)
__global__ __launch_bounds__(256) void k_init(uint32_t* __restrict__ ws) {
    const int i = blockIdx.x * 256 + threadIdx.x;
    if (i == 0) ws[0] = 0u;
    if (i < NCHUNK) ws[FLAGS_OFF_U32 + i] = 0u;
}

// ---- single-pass scan kernel
__global__ __launch_bounds__(256) void k_onepass(const f4* __restrict__ x,
                                                 const f4* __restrict__ s_init,
                                                 f4* __restrict__ out,
                                                 uint32_t* __restrict__ ws) {
    __shared__ f4 tot[16][16];     // [s][g] inclusive scan of per-thread totals
    __shared__ f4 off_lds[16];     // global offset per g
    __shared__ uint32_t tkt_lds;

    uint32_t* counter = ws;
    uint32_t* flags   = ws + FLAGS_OFF_U32;
    f4*       agg     = (f4*)(ws + AGG_OFF_U32);

    const int tid = threadIdx.x;
    if (tid == 0) tkt_lds = atomicAdd(counter, 1u);
    __syncthreads();
    const uint32_t ticket = tkt_lds;
    // b-major within k: ticket = k*128 + b -> chain link k-1 started ~128 tickets earlier
    const int b   = (int)(ticket & (B - 1));
    const int k   = (int)(ticket >> 7);
    const int cid = b * NC + k;

    const int s = tid >> 4;        // 0..15 t-subgroup
    const int g = tid & 15;        // 0..15 float4 channel group

    const size_t base = (size_t)cid * CH4 + (size_t)(s * VPT) * ROW4 + g;

    // load chunk slice into registers (32 VGPRs); nontemporal: x is streamed once
    f4 v[VPT];
    #pragma unroll
    for (int i = 0; i < VPT; ++i)
        v[i] = __builtin_nontemporal_load(&x[base + (size_t)i * ROW4]);

    f4 tsum = v[0];
    #pragma unroll
    for (int i = 1; i < VPT; ++i) tsum += v[i];

    // inclusive Hillis-Steele over s per g
    tot[s][g] = tsum;
    __syncthreads();
    f4 acc = tsum;
    #pragma unroll
    for (int d = 1; d < 16; d <<= 1) {
        if (s >= d) acc += tot[s - d][g];
        __syncthreads();
        tot[s][g] = acc;
        __syncthreads();
    }
    // tot[s][g] = inclusive; tot[15][g] = chunk aggregate

    // publish aggregate ASAP (before lookback) so successors never chain on us
    if (s == 15) {
        agg[(size_t)cid * 16 + g] = acc;       // one dwordx4 store across wave 3
        __threadfence();                        // drain + writeback before flag
        if (g == 0)
            __hip_atomic_store(&flags[cid], 1u, __ATOMIC_RELEASE,
                               __HIP_MEMORY_SCOPE_AGENT);
    }

    // lookback: wave 0 sums s_init + all predecessor aggregates (4 k's in flight)
    if (tid < 64) {
        const int gg    = tid & 15;
        const int kk_of = tid >> 4;            // 0..3
        f4 a = {0.f, 0.f, 0.f, 0.f};
        if (kk_of == 0) a = s_init[gg];        // seed ONCE (not per subgroup)
        for (int kk0 = 0; kk0 < k; kk0 += 4) {
            const int kk = kk0 + kk_of;
            if (kk < k) {
                const int pid = b * NC + kk;
                uint32_t spins = 0;
                bool ok = true;
                while (__hip_atomic_load(&flags[pid], __ATOMIC_ACQUIRE,
                                         __HIP_MEMORY_SCOPE_AGENT) == 0u) {
                    __builtin_amdgcn_s_sleep(2);
                    if (++spins > (1u << 20)) { ok = false; break; }
                }
                if (ok) {
                    a += agg[(size_t)pid * 16 + gg];
                } else {
                    // emergency: recompute predecessor aggregate from x (32 KB).
                    // Guarantees forward progress regardless of scheduling.
                    const size_t pb = (size_t)pid * CH4 + gg;
                    f4 t = {0.f, 0.f, 0.f, 0.f};
                    for (int tt = 0; tt < L; ++tt)
                        t += x[pb + (size_t)tt * ROW4];
                    a += t;
                }
            }
        }
        // reduce the 4 kk-subgroups (lanes xor 16, 32)
        #pragma unroll
        for (int m = 16; m <= 32; m <<= 1) {
            a.x += __shfl_xor(a.x, m, 64);
            a.y += __shfl_xor(a.y, m, 64);
            a.z += __shfl_xor(a.z, m, 64);
            a.w += __shfl_xor(a.w, m, 64);
        }
        if (tid < 16) off_lds[tid] = a;
    }
    __syncthreads();

    // final: global offset + exclusive-within-chunk + running sums; stream stores
    f4 run = off_lds[g];
    if (s > 0) run += tot[s - 1][g];
    #pragma unroll
    for (int i = 0; i < VPT; ++i) {
        run += v[i];
        __builtin_nontemporal_store(run, &out[base + (size_t)i * ROW4]);
    }
}

// ================= fallback: previous verified 2-pass path =================
__global__ __launch_bounds__(256) void k_partial(const f4* __restrict__ x,
                                                 f4* __restrict__ out) {
    const int tid   = blockIdx.x * 256 + threadIdx.x;
    const int chunk = tid >> 4;
    const int g     = tid & 15;
    const size_t base = (size_t)chunk * CH4 + g;
    f4 s = {0.f, 0.f, 0.f, 0.f};
    #pragma unroll 8
    for (int t = 0; t < L; ++t)
        s += x[base + (size_t)t * ROW4];
    out[base] = s;
}

__global__ __launch_bounds__(256) void k_scan(const f4* __restrict__ s_init,
                                              f4* __restrict__ out) {
    const int tid = blockIdx.x * 256 + threadIdx.x;
    const int b   = tid >> 4;
    const int g   = tid & 15;
    f4 off = s_init[g];
    size_t idx = (size_t)b * NC * CH4 + g;
    #pragma unroll 4
    for (int kk = 0; kk < NC; ++kk, idx += CH4) {
        const f4 p = out[idx];
        out[idx] = off;
        off += p;
    }
}

__global__ __launch_bounds__(256) void k_write(const f4* __restrict__ x,
                                               f4* __restrict__ out) {
    const int tid   = blockIdx.x * 256 + threadIdx.x;
    const int chunk = tid >> 4;
    const int g     = tid & 15;
    const size_t base = (size_t)chunk * CH4 + g;
    f4 run = out[base];
    #pragma unroll 8
    for (int t = 0; t < L; ++t) {
        run += x[base + (size_t)t * ROW4];
        __builtin_nontemporal_store(run, &out[base + (size_t)t * ROW4]);
    }
}

extern "C" void kernel_launch(void* const* d_in, const int* in_sizes, int n_in,
                              void* d_out, int out_size, void* d_ws, size_t ws_size,
                              hipStream_t stream) {
    const f4* x      = (const f4*)d_in[0];
    const f4* s_init = (const f4*)d_in[1];
    f4* out          = (f4*)d_out;

    if (d_ws != nullptr && ws_size >= WS_NEED) {
        uint32_t* ws = (uint32_t*)d_ws;
        k_init   <<<dim3((NCHUNK + 255) / 256), dim3(256), 0, stream>>>(ws);
        k_onepass<<<dim3(NCHUNK), dim3(256), 0, stream>>>(x, s_init, out, ws);
    } else {
        dim3 blk(256);
        k_partial<<<dim3(512), blk, 0, stream>>>(x, out);
        k_scan   <<<dim3(8),   blk, 0, stream>>>(s_init, out);
        k_write  <<<dim3(512), blk, 0, stream>>>(x, out);
    }
}

// Round 3
// 456.573 us; speedup vs baseline: 3.2358x; 3.2358x over previous
//
#include <hip/hip_runtime.h>

// CumSumLoop: x [B=128, T=8192, C=64] fp32, running cumsum over T, + s_init[C].
//
// Single-pass chained scan (decoupled aggregates + ticket ordering):
//   - one 256-thread block per 32 KB chunk (L=128 t-steps), x held in registers
//   - per-chunk two-level scan: 8-deep serial per thread, 16-wide Hillis-Steele in LDS
//   - chunk aggregate published BEFORE lookback; flat lookback over <=63 preds
//   - SYNC (round-3 fix): relaxed agent-scope atomics ONLY (global_* sc0 sc1 —
//     coherence-point access, NO L1/L2 invalidate or writeback). Release ordering
//     hand-built: payload atomics -> s_waitcnt vmcnt(0) -> flag atomic. Round 2's
//     ACQUIRE/RELEASE fences emitted whole-L2 inv/wb per poll -> 355 GB/s disaster.
//   - atomic ticket: lower tickets are resident-or-retired -> preds always publish
//   - bounded spin; on timeout recompute pred aggregate from x -> cannot hang.
// x fetched from HBM exactly once: ~545 MB total vs 805 MB for the 2-pass version.

typedef float f4 __attribute__((ext_vector_type(4)));
typedef unsigned long long u64;

#define B      128
#define T      8192
#define NC     64            // chunks along T per batch row
#define L      (T / NC)      // 128 t-steps per chunk
#define ROW4   16            // float4 per t-row (C=64)
#define CH4    (L * ROW4)    // 2048 float4 per chunk
#define NCHUNK (B * NC)      // 8192 chunks total
#define VPT    (L / 16)      // 8 t-rows per thread

// workspace layout (bytes):
//   [0]      u32 ticket counter
//   [256]    u32 flags[NCHUNK]                (32 KB)
//   [33024]  f4  agg[NCHUNK][16]              (2 MB)
#define FLAGS_OFF_U32 64
#define AGG_OFF_U32   8256
#define WS_NEED       (33024u + (size_t)NCHUNK * 16 * sizeof(f4))

#define AT_LD(p)    __hip_atomic_load((p),  __ATOMIC_RELAXED, __HIP_MEMORY_SCOPE_AGENT)
#define AT_ST(p,v)  __hip_atomic_store((p), (v), __ATOMIC_RELAXED, __HIP_MEMORY_SCOPE_AGENT)

// ---- init: zero ticket + flags each launch (graph-replay safe, stream-ordered)
__global__ __launch_bounds__(256) void k_init(uint32_t* __restrict__ ws) {
    const int i = blockIdx.x * 256 + threadIdx.x;
    if (i == 0) ws[0] = 0u;
    if (i < NCHUNK) ws[FLAGS_OFF_U32 + i] = 0u;
}

// ---- single-pass scan kernel
__global__ __launch_bounds__(256) void k_onepass(const f4* __restrict__ x,
                                                 const f4* __restrict__ s_init,
                                                 f4* __restrict__ out,
                                                 uint32_t* __restrict__ ws) {
    __shared__ f4 tot[16][16];     // [s][g] inclusive scan of per-thread totals
    __shared__ f4 off_lds[16];     // global offset per g
    __shared__ uint32_t tkt_lds;

    uint32_t* counter = ws;
    uint32_t* flags   = ws + FLAGS_OFF_U32;
    u64*      agg     = (u64*)(ws + AGG_OFF_U32);   // f4 payload as 2x u64

    const int tid = threadIdx.x;
    if (tid == 0) tkt_lds = atomicAdd(counter, 1u);
    __syncthreads();
    const uint32_t ticket = tkt_lds;
    // b-major within k: ticket = k*128 + b -> pred (k-1) started 128 tickets earlier
    const int b   = (int)(ticket & (B - 1));
    const int k   = (int)(ticket >> 7);
    const int cid = b * NC + k;

    const int s = tid >> 4;        // 0..15 t-subgroup
    const int g = tid & 15;        // 0..15 float4 channel group

    const size_t base = (size_t)cid * CH4 + (size_t)(s * VPT) * ROW4 + g;

    // load chunk slice into registers (32 VGPRs); nontemporal: x is streamed once
    f4 v[VPT];
    #pragma unroll
    for (int i = 0; i < VPT; ++i)
        v[i] = __builtin_nontemporal_load(&x[base + (size_t)i * ROW4]);

    f4 tsum = v[0];
    #pragma unroll
    for (int i = 1; i < VPT; ++i) tsum += v[i];

    // inclusive Hillis-Steele over s per g
    tot[s][g] = tsum;
    __syncthreads();
    f4 acc = tsum;
    #pragma unroll
    for (int d = 1; d < 16; d <<= 1) {
        if (s >= d) acc += tot[s - d][g];
        __syncthreads();
        tot[s][g] = acc;
        __syncthreads();
    }
    // tot[s][g] = inclusive; tot[15][g] = chunk aggregate

    // publish aggregate ASAP (before lookback). Payload via relaxed coherence-point
    // atomics; vmcnt(0) guarantees payload reached L3 before the flag is issued.
    if (s == 15) {
        union { f4 v; u64 u[2]; } pk; pk.v = acc;
        u64* ap = &agg[((size_t)cid * 16 + g) * 2];
        AT_ST(&ap[0], pk.u[0]);
        AT_ST(&ap[1], pk.u[1]);
        asm volatile("s_waitcnt vmcnt(0)" ::: "memory");
        if (g == 0) AT_ST(&flags[cid], 1u);
    }

    // lookback: wave 0 sums s_init + all predecessor aggregates (4 k's in flight)
    if (tid < 64) {
        const int gg    = tid & 15;
        const int kk_of = tid >> 4;            // 0..3
        f4 a = {0.f, 0.f, 0.f, 0.f};
        if (kk_of == 0) a = s_init[gg];        // seed once (not per subgroup)
        for (int kk0 = 0; kk0 < k; kk0 += 4) {
            const int kk = kk0 + kk_of;
            if (kk < k) {
                const int pid = b * NC + kk;
                uint32_t spins = 0;
                bool ok = true;
                while (AT_LD(&flags[pid]) == 0u) {
                    __builtin_amdgcn_s_sleep(4);
                    if (++spins > (1u << 18)) { ok = false; break; }
                }
                asm volatile("" ::: "memory");  // no payload-load hoist above poll
                if (ok) {
                    u64* ap = &agg[((size_t)pid * 16 + gg) * 2];
                    union { f4 v; u64 u[2]; } pk;
                    pk.u[0] = AT_LD(&ap[0]);
                    pk.u[1] = AT_LD(&ap[1]);
                    a += pk.v;
                } else {
                    // emergency: recompute pred aggregate from x (32 KB).
                    // Guarantees forward progress regardless of scheduling.
                    const size_t pb = (size_t)pid * CH4 + gg;
                    f4 t = {0.f, 0.f, 0.f, 0.f};
                    for (int tt = 0; tt < L; ++tt)
                        t += x[pb + (size_t)tt * ROW4];
                    a += t;
                }
            }
        }
        // reduce the 4 kk-subgroups (lanes xor 16, 32)
        #pragma unroll
        for (int m = 16; m <= 32; m <<= 1) {
            a.x += __shfl_xor(a.x, m, 64);
            a.y += __shfl_xor(a.y, m, 64);
            a.z += __shfl_xor(a.z, m, 64);
            a.w += __shfl_xor(a.w, m, 64);
        }
        if (tid < 16) off_lds[tid] = a;
    }
    __syncthreads();

    // final: global offset + exclusive-within-chunk + running sums; stream stores
    f4 run = off_lds[g];
    if (s > 0) run += tot[s - 1][g];
    #pragma unroll
    for (int i = 0; i < VPT; ++i) {
        run += v[i];
        __builtin_nontemporal_store(run, &out[base + (size_t)i * ROW4]);
    }
}

// ================= fallback: previous verified 2-pass path =================
__global__ __launch_bounds__(256) void k_partial(const f4* __restrict__ x,
                                                 f4* __restrict__ out) {
    const int tid   = blockIdx.x * 256 + threadIdx.x;
    const int chunk = tid >> 4;
    const int g     = tid & 15;
    const size_t base = (size_t)chunk * CH4 + g;
    f4 s = {0.f, 0.f, 0.f, 0.f};
    #pragma unroll 8
    for (int t = 0; t < L; ++t)
        s += x[base + (size_t)t * ROW4];
    out[base] = s;
}

__global__ __launch_bounds__(256) void k_scan(const f4* __restrict__ s_init,
                                              f4* __restrict__ out) {
    const int tid = blockIdx.x * 256 + threadIdx.x;
    const int b   = tid >> 4;
    const int g   = tid & 15;
    f4 off = s_init[g];
    size_t idx = (size_t)b * NC * CH4 + g;
    #pragma unroll 4
    for (int kk = 0; kk < NC; ++kk, idx += CH4) {
        const f4 p = out[idx];
        out[idx] = off;
        off += p;
    }
}

__global__ __launch_bounds__(256) void k_write(const f4* __restrict__ x,
                                               f4* __restrict__ out) {
    const int tid   = blockIdx.x * 256 + threadIdx.x;
    const int chunk = tid >> 4;
    const int g     = tid & 15;
    const size_t base = (size_t)chunk * CH4 + g;
    f4 run = out[base];
    #pragma unroll 8
    for (int t = 0; t < L; ++t) {
        run += x[base + (size_t)t * ROW4];
        __builtin_nontemporal_store(run, &out[base + (size_t)t * ROW4]);
    }
}

extern "C" void kernel_launch(void* const* d_in, const int* in_sizes, int n_in,
                              void* d_out, int out_size, void* d_ws, size_t ws_size,
                              hipStream_t stream) {
    const f4* x      = (const f4*)d_in[0];
    const f4* s_init = (const f4*)d_in[1];
    f4* out          = (f4*)d_out;

    if (d_ws != nullptr && ws_size >= WS_NEED) {
        uint32_t* ws = (uint32_t*)d_ws;
        k_init   <<<dim3((NCHUNK + 255) / 256), dim3(256), 0, stream>>>(ws);
        k_onepass<<<dim3(NCHUNK), dim3(256), 0, stream>>>(x, s_init, out, ws);
    } else {
        dim3 blk(256);
        k_partial<<<dim3(512), blk, 0, stream>>>(x, out);
        k_scan   <<<dim3(8),   blk, 0, stream>>>(s_init, out);
        k_write  <<<dim3(512), blk, 0, stream>>>(x, out);
    }
}

// Round 4
// 445.885 us; speedup vs baseline: 3.3133x; 1.0240x over previous
//
#include <hip/hip_runtime.h>

// CumSumLoop: x [B=128, T=8192, C=64] fp32, running cumsum over T, + s_init[C].
//
// Single-pass chained scan (decoupled aggregates + ticket ordering):
//   - one 256-thread block per 32 KB chunk (L=128 t-steps), x held in registers
//   - per-chunk two-level scan: 8-deep serial per thread, 16-wide Hillis-Steele in LDS
//   - chunk aggregate published BEFORE lookback; flat lookback over <=63 preds
//   - SYNC: relaxed agent-scope atomics ONLY (coherence-point access, no L1/L2
//     inv/wb). Release ordering hand-built: payload -> s_waitcnt vmcnt(0) -> flag.
//   - ROUND-4: lookback parallelized over all 256 threads (16 kk-slots wide,
//     4 rounds) with poll-phase separated from load-phase -> dependent L3
//     round-trips per block drop ~32 -> ~6. Round 3 used 64 lanes / 16 serial
//     poll+load rounds: ~8-10 us of unhidden per-block latency.
//   - atomic ticket: lower tickets are resident-or-retired -> preds always publish
//   - bounded spin; on timeout recompute pred aggregate from x -> cannot hang.
// x fetched from HBM exactly once: ~414 MB measured total (x reads part-L3-hit).

typedef float f4 __attribute__((ext_vector_type(4)));
typedef unsigned long long u64;

#define B      128
#define T      8192
#define NC     64            // chunks along T per batch row
#define L      (T / NC)      // 128 t-steps per chunk
#define ROW4   16            // float4 per t-row (C=64)
#define CH4    (L * ROW4)    // 2048 float4 per chunk
#define NCHUNK (B * NC)      // 8192 chunks total
#define VPT    (L / 16)      // 8 t-rows per thread

// workspace layout (bytes):
//   [0]      u32 ticket counter
//   [256]    u32 flags[NCHUNK]                (32 KB)
//   [33024]  f4  agg[NCHUNK][16]              (2 MB)
#define FLAGS_OFF_U32 64
#define AGG_OFF_U32   8256
#define WS_NEED       (33024u + (size_t)NCHUNK * 16 * sizeof(f4))

#define AT_LD(p)    __hip_atomic_load((p),  __ATOMIC_RELAXED, __HIP_MEMORY_SCOPE_AGENT)
#define AT_ST(p,v)  __hip_atomic_store((p), (v), __ATOMIC_RELAXED, __HIP_MEMORY_SCOPE_AGENT)

// ---- init: zero ticket + flags each launch (graph-replay safe, stream-ordered;
//      required because the harness may re-poison ws between iterations)
__global__ __launch_bounds__(256) void k_init(uint32_t* __restrict__ ws) {
    const int i = blockIdx.x * 256 + threadIdx.x;
    if (i == 0) ws[0] = 0u;
    if (i < NCHUNK) ws[FLAGS_OFF_U32 + i] = 0u;
}

// ---- single-pass scan kernel
__global__ __launch_bounds__(256) void k_onepass(const f4* __restrict__ x,
                                                 const f4* __restrict__ s_init,
                                                 f4* __restrict__ out,
                                                 uint32_t* __restrict__ ws) {
    __shared__ f4 tot[16][16];     // [s][g] inclusive scan of per-thread totals
    __shared__ f4 part[16][16];    // [q][g] lookback partials
    __shared__ f4 part2[4][16];    // second-level reduce
    __shared__ f4 off_lds[16];     // global offset per g
    __shared__ uint32_t tkt_lds;

    uint32_t* counter = ws;
    uint32_t* flags   = ws + FLAGS_OFF_U32;
    u64*      agg     = (u64*)(ws + AGG_OFF_U32);   // f4 payload as 2x u64

    const int tid = threadIdx.x;
    if (tid == 0) tkt_lds = atomicAdd(counter, 1u);

    const int s = tid >> 4;        // 0..15 t-subgroup (also lookback kk-slot q)
    const int g = tid & 15;        // 0..15 float4 channel group
    const f4 si = s_init[g];       // tiny, L2-hot; needed by tid<16 later

    __syncthreads();
    const uint32_t ticket = tkt_lds;
    // b-major within k: ticket = k*128 + b -> pred (k-1) started 128 tickets earlier
    const int b   = (int)(ticket & (B - 1));
    const int k   = (int)(ticket >> 7);
    const int cid = b * NC + k;

    const size_t base = (size_t)cid * CH4 + (size_t)(s * VPT) * ROW4 + g;

    // load chunk slice into registers (32 VGPRs); nontemporal: x is streamed once
    f4 v[VPT];
    #pragma unroll
    for (int i = 0; i < VPT; ++i)
        v[i] = __builtin_nontemporal_load(&x[base + (size_t)i * ROW4]);

    f4 tsum = v[0];
    #pragma unroll
    for (int i = 1; i < VPT; ++i) tsum += v[i];

    // inclusive Hillis-Steele over s per g
    tot[s][g] = tsum;
    __syncthreads();
    f4 acc = tsum;
    #pragma unroll
    for (int d = 1; d < 16; d <<= 1) {
        if (s >= d) acc += tot[s - d][g];
        __syncthreads();
        tot[s][g] = acc;
        __syncthreads();
    }
    // tot[s][g] = inclusive; tot[15][g] = chunk aggregate

    // publish aggregate ASAP (before lookback). Payload via relaxed coherence-point
    // atomics; vmcnt(0) guarantees payload reached L3 before the flag is issued.
    if (s == 15) {
        union { f4 v; u64 u[2]; } pk; pk.v = acc;
        u64* ap = &agg[((size_t)cid * 16 + g) * 2];
        AT_ST(&ap[0], pk.u[0]);
        AT_ST(&ap[1], pk.u[1]);
        asm volatile("s_waitcnt vmcnt(0)" ::: "memory");
        if (g == 0) AT_ST(&flags[cid], 1u);
    }

    // ---- lookback: ALL 256 threads. Thread (q=s, g) covers kk = q + 16r.
    // Phase 1: poll the (<=4) needed flags. Phase 2: 4 INDEPENDENT agg loads.
    uint32_t pend = 0;
    #pragma unroll
    for (int r = 0; r < 4; ++r) {
        const int kk = s + (r << 4);
        if (kk < k) {
            const int pid = b * NC + kk;
            uint32_t spins = 0;
            while (AT_LD(&flags[pid]) == 0u) {
                __builtin_amdgcn_s_sleep(1);
                if (++spins > (1u << 18)) { pend |= 1u << r; break; }
            }
        }
    }
    asm volatile("" ::: "memory");  // no payload-load hoist above polls
    f4 a = {0.f, 0.f, 0.f, 0.f};
    #pragma unroll
    for (int r = 0; r < 4; ++r) {
        const int kk = s + (r << 4);
        if (kk < k) {
            const int pid = b * NC + kk;
            if (!(pend & (1u << r))) {
                u64* ap = &agg[((size_t)pid * 16 + g) * 2];
                union { f4 v; u64 u[2]; } pk;
                pk.u[0] = AT_LD(&ap[0]);
                pk.u[1] = AT_LD(&ap[1]);
                a += pk.v;
            } else {
                // emergency: recompute pred aggregate from x (32 KB).
                // Guarantees forward progress regardless of scheduling.
                const size_t pb = (size_t)pid * CH4 + g;
                f4 t = {0.f, 0.f, 0.f, 0.f};
                for (int tt = 0; tt < L; ++tt)
                    t += x[pb + (size_t)tt * ROW4];
                a += t;
            }
        }
    }
    part[s][g] = a;
    __syncthreads();
    // 2-level LDS reduce over the 16 kk-slots
    if (tid < 64) {
        const int u  = tid >> 4;   // 0..3
        const int gg = tid & 15;
        part2[u][gg] = part[4 * u + 0][gg] + part[4 * u + 1][gg]
                     + part[4 * u + 2][gg] + part[4 * u + 3][gg];
    }
    __syncthreads();
    if (tid < 16)
        off_lds[tid] = si + part2[0][tid] + part2[1][tid]
                          + part2[2][tid] + part2[3][tid];
    __syncthreads();

    // final: global offset + exclusive-within-chunk + running sums; stream stores
    f4 run = off_lds[g];
    if (s > 0) run += tot[s - 1][g];
    #pragma unroll
    for (int i = 0; i < VPT; ++i) {
        run += v[i];
        __builtin_nontemporal_store(run, &out[base + (size_t)i * ROW4]);
    }
}

// ================= fallback: previous verified 2-pass path =================
__global__ __launch_bounds__(256) void k_partial(const f4* __restrict__ x,
                                                 f4* __restrict__ out) {
    const int tid   = blockIdx.x * 256 + threadIdx.x;
    const int chunk = tid >> 4;
    const int g     = tid & 15;
    const size_t base = (size_t)chunk * CH4 + g;
    f4 s = {0.f, 0.f, 0.f, 0.f};
    #pragma unroll 8
    for (int t = 0; t < L; ++t)
        s += x[base + (size_t)t * ROW4];
    out[base] = s;
}

__global__ __launch_bounds__(256) void k_scan(const f4* __restrict__ s_init,
                                              f4* __restrict__ out) {
    const int tid = blockIdx.x * 256 + threadIdx.x;
    const int b   = tid >> 4;
    const int g   = tid & 15;
    f4 off = s_init[g];
    size_t idx = (size_t)b * NC * CH4 + g;
    #pragma unroll 4
    for (int kk = 0; kk < NC; ++kk, idx += CH4) {
        const f4 p = out[idx];
        out[idx] = off;
        off += p;
    }
}

__global__ __launch_bounds__(256) void k_write(const f4* __restrict__ x,
                                               f4* __restrict__ out) {
    const int tid   = blockIdx.x * 256 + threadIdx.x;
    const int chunk = tid >> 4;
    const int g     = tid & 15;
    const size_t base = (size_t)chunk * CH4 + g;
    f4 run = out[base];
    #pragma unroll 8
    for (int t = 0; t < L; ++t) {
        run += x[base + (size_t)t * ROW4];
        __builtin_nontemporal_store(run, &out[base + (size_t)t * ROW4]);
    }
}

extern "C" void kernel_launch(void* const* d_in, const int* in_sizes, int n_in,
                              void* d_out, int out_size, void* d_ws, size_t ws_size,
                              hipStream_t stream) {
    const f4* x      = (const f4*)d_in[0];
    const f4* s_init = (const f4*)d_in[1];
    f4* out          = (f4*)d_out;

    if (d_ws != nullptr && ws_size >= WS_NEED) {
        uint32_t* ws = (uint32_t*)d_ws;
        k_init   <<<dim3((NCHUNK + 255) / 256), dim3(256), 0, stream>>>(ws);
        k_onepass<<<dim3(NCHUNK), dim3(256), 0, stream>>>(x, s_init, out, ws);
    } else {
        dim3 blk(256);
        k_partial<<<dim3(512), blk, 0, stream>>>(x, out);
        k_scan   <<<dim3(8),   blk, 0, stream>>>(s_init, out);
        k_write  <<<dim3(512), blk, 0, stream>>>(x, out);
    }
}

// Round 5
// 426.698 us; speedup vs baseline: 3.4623x; 1.0450x over previous
//
#include <hip/hip_runtime.h>

// CumSumLoop: x [B=128, T=8192, C=64] fp32, running cumsum over T, + s_init[C].
//
// Single-pass chained scan (decoupled aggregates, flat lookback):
//   - one 256-thread block per 32 KB chunk (L=128 t-steps), x held in registers
//   - per-chunk scan: 8-deep serial per thread, 16-wide Hillis-Steele in LDS
//   - SYNC: relaxed agent-scope atomics ONLY (coherence-point, no L1/L2 inv/wb).
//     Release ordering hand-built: payload stores -> s_waitcnt vmcnt(0) -> flag.
//   - ROUND-5: (a) ticket atomic REMOVED — cid straight from blockIdx (8192
//     blocks on one atomic cacheline serialized kernel start AND made x-loads
//     data-dependent on an L3 round trip). Dispatch-order insurance is now the
//     bounded-spin + recompute-from-x path (cannot hang, only slow).
//     (b) EARLY PUBLISH: aggregate computed by wave 0 right after barrier 1
//     (LDS reads + 2 shuffle levels), payload stores drain to L3 DURING the
//     scan, flag released right after the scan -> successors' polls hit ready.
//   - lookback: all 256 threads, 16 kk-slots wide, poll-phase split from
//     load-phase -> ~2 dependent L3 round trips total.
// x fetched from HBM exactly once; ~414 MB total measured traffic.

typedef float f4 __attribute__((ext_vector_type(4)));
typedef unsigned long long u64;

#define B      128
#define T      8192
#define NC     64            // chunks along T per batch row
#define L      (T / NC)      // 128 t-steps per chunk
#define ROW4   16            // float4 per t-row (C=64)
#define CH4    (L * ROW4)    // 2048 float4 per chunk
#define NCHUNK (B * NC)      // 8192 chunks total
#define VPT    (L / 16)      // 8 t-rows per thread

// workspace layout (bytes):
//   [0]      u32 (unused, was ticket)
//   [256]    u32 flags[NCHUNK]                (32 KB)
//   [33024]  f4  agg[NCHUNK][16]              (2 MB)
#define FLAGS_OFF_U32 64
#define AGG_OFF_U32   8256
#define WS_NEED       (33024u + (size_t)NCHUNK * 16 * sizeof(f4))

#define AT_LD(p)    __hip_atomic_load((p),  __ATOMIC_RELAXED, __HIP_MEMORY_SCOPE_AGENT)
#define AT_ST(p,v)  __hip_atomic_store((p), (v), __ATOMIC_RELAXED, __HIP_MEMORY_SCOPE_AGENT)

// ---- init: zero flags each launch (graph-replay safe, stream-ordered;
//      required because the harness may re-poison ws between iterations)
__global__ __launch_bounds__(256) void k_init(uint32_t* __restrict__ ws) {
    const int i = blockIdx.x * 256 + threadIdx.x;
    if (i == 0) ws[0] = 0u;
    if (i < NCHUNK) ws[FLAGS_OFF_U32 + i] = 0u;
}

// ---- single-pass scan kernel
__global__ __launch_bounds__(256) void k_onepass(const f4* __restrict__ x,
                                                 const f4* __restrict__ s_init,
                                                 f4* __restrict__ out,
                                                 uint32_t* __restrict__ ws) {
    __shared__ f4 tot[16][16];     // [s][g] inclusive scan of per-thread totals
    __shared__ f4 part[16][16];    // [q][g] lookback partials
    __shared__ f4 part2[4][16];    // second-level reduce
    __shared__ f4 off_lds[16];     // global offset per g

    uint32_t* flags = ws + FLAGS_OFF_U32;
    u64*      agg   = (u64*)(ws + AGG_OFF_U32);   // f4 payload as 2x u64

    const int tid = threadIdx.x;
    // b-major within k: wgid = k*128 + b -> pred (k-1,b) dispatched 128 wgids earlier
    const int wgid = blockIdx.x;
    const int b    = wgid & (B - 1);
    const int k    = wgid >> 7;
    const int cid  = b * NC + k;

    const int s = tid >> 4;        // 0..15 t-subgroup (also lookback kk-slot)
    const int g = tid & 15;        // 0..15 float4 channel group

    const size_t base = (size_t)cid * CH4 + (size_t)(s * VPT) * ROW4 + g;

    // load chunk slice into registers (32 VGPRs); nontemporal: x is streamed once.
    // Issues in the first instructions — no atomic/barrier ahead of it.
    f4 v[VPT];
    #pragma unroll
    for (int i = 0; i < VPT; ++i)
        v[i] = __builtin_nontemporal_load(&x[base + (size_t)i * ROW4]);

    const f4 si = s_init[g];       // tiny, L2-hot; used by tid<16 later

    f4 tsum = v[0];
    #pragma unroll
    for (int i = 1; i < VPT; ++i) tsum += v[i];

    tot[s][g] = tsum;
    __syncthreads();               // B1

    // ---- EARLY PUBLISH (wave 0): aggregate per g = sum over all 16 s.
    // Payload stores issued now; they drain to L3 while the scan below runs.
    if (tid < 64) {
        const int q  = tid >> 4;   // 0..3
        const int gg = tid & 15;
        f4 ag = tot[4 * q + 0][gg] + tot[4 * q + 1][gg]
              + tot[4 * q + 2][gg] + tot[4 * q + 3][gg];
        ag.x += __shfl_xor(ag.x, 16, 64); ag.y += __shfl_xor(ag.y, 16, 64);
        ag.z += __shfl_xor(ag.z, 16, 64); ag.w += __shfl_xor(ag.w, 16, 64);
        ag.x += __shfl_xor(ag.x, 32, 64); ag.y += __shfl_xor(ag.y, 32, 64);
        ag.z += __shfl_xor(ag.z, 32, 64); ag.w += __shfl_xor(ag.w, 32, 64);
        if (q == 0) {
            union { f4 v; u64 u[2]; } pk; pk.v = ag;
            u64* ap = &agg[((size_t)cid * 16 + gg) * 2];
            AT_ST(&ap[0], pk.u[0]);
            AT_ST(&ap[1], pk.u[1]);
        }
    }

    // inclusive Hillis-Steele over s per g
    f4 acc = tsum;
    #pragma unroll
    for (int d = 1; d < 16; d <<= 1) {
        if (s >= d) acc += tot[s - d][g];
        __syncthreads();
        tot[s][g] = acc;
        __syncthreads();
    }
    // tot[s][g] = inclusive over s

    // release flag: payload stores (issued by wave 0 pre-scan) are long drained.
    if (tid == 0) {
        asm volatile("s_waitcnt vmcnt(0)" ::: "memory");
        AT_ST(&flags[cid], 1u);
    }

    // ---- lookback: ALL 256 threads. Thread (q=s, g) covers kk = s + 16r.
    // Phase 1: poll the (<=4) needed flags. Phase 2: 4 INDEPENDENT agg loads.
    uint32_t pend = 0;
    #pragma unroll
    for (int r = 0; r < 4; ++r) {
        const int kk = s + (r << 4);
        if (kk < k) {
            const int pid = b * NC + kk;
            uint32_t spins = 0;
            while (AT_LD(&flags[pid]) == 0u) {
                __builtin_amdgcn_s_sleep(1);
                if (++spins > (1u << 18)) { pend |= 1u << r; break; }
            }
        }
    }
    asm volatile("" ::: "memory");  // no payload-load hoist above polls
    f4 a = {0.f, 0.f, 0.f, 0.f};
    #pragma unroll
    for (int r = 0; r < 4; ++r) {
        const int kk = s + (r << 4);
        if (kk < k) {
            const int pid = b * NC + kk;
            if (!(pend & (1u << r))) {
                u64* ap = &agg[((size_t)pid * 16 + g) * 2];
                union { f4 v; u64 u[2]; } pk;
                pk.u[0] = AT_LD(&ap[0]);
                pk.u[1] = AT_LD(&ap[1]);
                a += pk.v;
            } else {
                // emergency: recompute pred aggregate from x (32 KB).
                // Guarantees forward progress regardless of scheduling.
                const size_t pb = (size_t)pid * CH4 + g;
                f4 t = {0.f, 0.f, 0.f, 0.f};
                for (int tt = 0; tt < L; ++tt)
                    t += x[pb + (size_t)tt * ROW4];
                a += t;
            }
        }
    }
    part[s][g] = a;
    __syncthreads();
    // 2-level LDS reduce over the 16 kk-slots
    if (tid < 64) {
        const int u  = tid >> 4;   // 0..3
        const int gg = tid & 15;
        part2[u][gg] = part[4 * u + 0][gg] + part[4 * u + 1][gg]
                     + part[4 * u + 2][gg] + part[4 * u + 3][gg];
    }
    __syncthreads();
    if (tid < 16)
        off_lds[tid] = si + part2[0][tid] + part2[1][tid]
                          + part2[2][tid] + part2[3][tid];
    __syncthreads();

    // final: global offset + exclusive-within-chunk + running sums; stream stores
    f4 run = off_lds[g];
    if (s > 0) run += tot[s - 1][g];
    #pragma unroll
    for (int i = 0; i < VPT; ++i) {
        run += v[i];
        __builtin_nontemporal_store(run, &out[base + (size_t)i * ROW4]);
    }
}

// ================= fallback: previous verified 2-pass path =================
__global__ __launch_bounds__(256) void k_partial(const f4* __restrict__ x,
                                                 f4* __restrict__ out) {
    const int tid   = blockIdx.x * 256 + threadIdx.x;
    const int chunk = tid >> 4;
    const int g     = tid & 15;
    const size_t base = (size_t)chunk * CH4 + g;
    f4 s = {0.f, 0.f, 0.f, 0.f};
    #pragma unroll 8
    for (int t = 0; t < L; ++t)
        s += x[base + (size_t)t * ROW4];
    out[base] = s;
}

__global__ __launch_bounds__(256) void k_scan(const f4* __restrict__ s_init,
                                              f4* __restrict__ out) {
    const int tid = blockIdx.x * 256 + threadIdx.x;
    const int b   = tid >> 4;
    const int g   = tid & 15;
    f4 off = s_init[g];
    size_t idx = (size_t)b * NC * CH4 + g;
    #pragma unroll 4
    for (int kk = 0; kk < NC; ++kk, idx += CH4) {
        const f4 p = out[idx];
        out[idx] = off;
        off += p;
    }
}

__global__ __launch_bounds__(256) void k_write(const f4* __restrict__ x,
                                               f4* __restrict__ out) {
    const int tid   = blockIdx.x * 256 + threadIdx.x;
    const int chunk = tid >> 4;
    const int g     = tid & 15;
    const size_t base = (size_t)chunk * CH4 + g;
    f4 run = out[base];
    #pragma unroll 8
    for (int t = 0; t < L; ++t) {
        run += x[base + (size_t)t * ROW4];
        __builtin_nontemporal_store(run, &out[base + (size_t)t * ROW4]);
    }
}

extern "C" void kernel_launch(void* const* d_in, const int* in_sizes, int n_in,
                              void* d_out, int out_size, void* d_ws, size_t ws_size,
                              hipStream_t stream) {
    const f4* x      = (const f4*)d_in[0];
    const f4* s_init = (const f4*)d_in[1];
    f4* out          = (f4*)d_out;

    if (d_ws != nullptr && ws_size >= WS_NEED) {
        uint32_t* ws = (uint32_t*)d_ws;
        k_init   <<<dim3((NCHUNK + 255) / 256), dim3(256), 0, stream>>>(ws);
        k_onepass<<<dim3(NCHUNK), dim3(256), 0, stream>>>(x, s_init, out, ws);
    } else {
        dim3 blk(256);
        k_partial<<<dim3(512), blk, 0, stream>>>(x, out);
        k_scan   <<<dim3(8),   blk, 0, stream>>>(s_init, out);
        k_write  <<<dim3(512), blk, 0, stream>>>(x, out);
    }
}

// Round 6
// 421.193 us; speedup vs baseline: 3.5076x; 1.0131x over previous
//
#include <hip/hip_runtime.h>

// CumSumLoop: x [B=128, T=8192, C=64] fp32, running cumsum over T, + s_init[C].
//
// Single-pass chained scan (decoupled aggregates, flat lookback):
//   - ROUND-6: fatter chunks — NC 64->32, L 128->256, VPT 8->16 (64 KB / block).
//     Halves per-block sync overhead relative to streaming work, halves the
//     chain depth (lookback <=31 preds, 2 poll rounds), same compulsory traffic.
//   - one 256-thread block per 64 KB chunk, x held in registers (v[16] = 64 VGPR)
//   - per-chunk scan: 16-deep serial per thread, 16-wide Hillis-Steele in LDS
//   - SYNC: relaxed agent-scope atomics ONLY (coherence-point, no L1/L2 inv/wb).
//     Release ordering hand-built: payload stores -> s_waitcnt vmcnt(0) -> flag.
//   - EARLY PUBLISH: wave 0 computes the chunk aggregate right after barrier 1
//     (LDS reads + 2 shuffle levels); payload stores drain to L3 DURING the
//     scan; flag released right after the scan.
//   - no global atomics in the hot path; cid straight from blockIdx.
//   - bounded spin; on timeout recompute pred aggregate from x -> cannot hang.
// x fetched from HBM exactly once; ~410 MB total measured traffic.

typedef float f4 __attribute__((ext_vector_type(4)));
typedef unsigned long long u64;

#define B      128
#define T      8192
#define NC     32            // chunks along T per batch row
#define L      (T / NC)      // 256 t-steps per chunk
#define ROW4   16            // float4 per t-row (C=64)
#define CH4    (L * ROW4)    // 4096 float4 per chunk
#define NCHUNK (B * NC)      // 4096 chunks total
#define VPT    (L / 16)      // 16 t-rows per thread

// workspace layout (bytes):
//   [0]      u32 (unused)
//   [256]    u32 flags[NCHUNK]                (16 KB)
//   [33024]  f4  agg[NCHUNK][16]              (1 MB)
#define FLAGS_OFF_U32 64
#define AGG_OFF_U32   8256
#define WS_NEED       (33024u + (size_t)NCHUNK * 16 * sizeof(f4))

#define AT_LD(p)    __hip_atomic_load((p),  __ATOMIC_RELAXED, __HIP_MEMORY_SCOPE_AGENT)
#define AT_ST(p,v)  __hip_atomic_store((p), (v), __ATOMIC_RELAXED, __HIP_MEMORY_SCOPE_AGENT)

// ---- init: zero flags each launch (graph-replay safe, stream-ordered;
//      required because the harness may re-poison ws between iterations)
__global__ __launch_bounds__(256) void k_init(uint32_t* __restrict__ ws) {
    const int i = blockIdx.x * 256 + threadIdx.x;
    if (i == 0) ws[0] = 0u;
    if (i < NCHUNK) ws[FLAGS_OFF_U32 + i] = 0u;
}

// ---- single-pass scan kernel
__global__ __launch_bounds__(256) void k_onepass(const f4* __restrict__ x,
                                                 const f4* __restrict__ s_init,
                                                 f4* __restrict__ out,
                                                 uint32_t* __restrict__ ws) {
    __shared__ f4 tot[16][16];     // [s][g] inclusive scan of per-thread totals
    __shared__ f4 part[16][16];    // [q][g] lookback partials
    __shared__ f4 part2[4][16];    // second-level reduce
    __shared__ f4 off_lds[16];     // global offset per g

    uint32_t* flags = ws + FLAGS_OFF_U32;
    u64*      agg   = (u64*)(ws + AGG_OFF_U32);   // f4 payload as 2x u64

    const int tid = threadIdx.x;
    // b-major within k: wgid = k*128 + b -> pred (k-1,b) dispatched 128 wgids earlier
    const int wgid = blockIdx.x;
    const int b    = wgid & (B - 1);
    const int k    = wgid >> 7;
    const int cid  = b * NC + k;

    const int s = tid >> 4;        // 0..15 t-subgroup (also lookback kk-slot)
    const int g = tid & 15;        // 0..15 float4 channel group

    const size_t base = (size_t)cid * CH4 + (size_t)(s * VPT) * ROW4 + g;

    // load chunk slice into registers (64 VGPRs); nontemporal: x is streamed once.
    // Issues in the first instructions — no atomic/barrier ahead of it.
    f4 v[VPT];
    #pragma unroll
    for (int i = 0; i < VPT; ++i)
        v[i] = __builtin_nontemporal_load(&x[base + (size_t)i * ROW4]);

    const f4 si = s_init[g];       // tiny, L2-hot; used by tid<16 later

    f4 tsum = v[0];
    #pragma unroll
    for (int i = 1; i < VPT; ++i) tsum += v[i];

    tot[s][g] = tsum;
    __syncthreads();               // B1

    // ---- EARLY PUBLISH (wave 0): aggregate per g = sum over all 16 s.
    // Payload stores issued now; they drain to L3 while the scan below runs.
    if (tid < 64) {
        const int q  = tid >> 4;   // 0..3
        const int gg = tid & 15;
        f4 ag = tot[4 * q + 0][gg] + tot[4 * q + 1][gg]
              + tot[4 * q + 2][gg] + tot[4 * q + 3][gg];
        ag.x += __shfl_xor(ag.x, 16, 64); ag.y += __shfl_xor(ag.y, 16, 64);
        ag.z += __shfl_xor(ag.z, 16, 64); ag.w += __shfl_xor(ag.w, 16, 64);
        ag.x += __shfl_xor(ag.x, 32, 64); ag.y += __shfl_xor(ag.y, 32, 64);
        ag.z += __shfl_xor(ag.z, 32, 64); ag.w += __shfl_xor(ag.w, 32, 64);
        if (q == 0) {
            union { f4 v; u64 u[2]; } pk; pk.v = ag;
            u64* ap = &agg[((size_t)cid * 16 + gg) * 2];
            AT_ST(&ap[0], pk.u[0]);
            AT_ST(&ap[1], pk.u[1]);
        }
    }

    // inclusive Hillis-Steele over s per g
    f4 acc = tsum;
    #pragma unroll
    for (int d = 1; d < 16; d <<= 1) {
        if (s >= d) acc += tot[s - d][g];
        __syncthreads();
        tot[s][g] = acc;
        __syncthreads();
    }
    // tot[s][g] = inclusive over s

    // release flag: payload stores (issued by wave 0 pre-scan) are long drained.
    if (tid == 0) {
        asm volatile("s_waitcnt vmcnt(0)" ::: "memory");
        AT_ST(&flags[cid], 1u);
    }

    // ---- lookback: ALL 256 threads. Thread (q=s, g) covers kk = s + 16r, r<2.
    // Phase 1: poll the (<=2) needed flags. Phase 2: INDEPENDENT agg loads.
    uint32_t pend = 0;
    #pragma unroll
    for (int r = 0; r < 2; ++r) {
        const int kk = s + (r << 4);
        if (kk < k) {
            const int pid = b * NC + kk;
            uint32_t spins = 0;
            while (AT_LD(&flags[pid]) == 0u) {
                __builtin_amdgcn_s_sleep(1);
                if (++spins > (1u << 18)) { pend |= 1u << r; break; }
            }
        }
    }
    asm volatile("" ::: "memory");  // no payload-load hoist above polls
    f4 a = {0.f, 0.f, 0.f, 0.f};
    #pragma unroll
    for (int r = 0; r < 2; ++r) {
        const int kk = s + (r << 4);
        if (kk < k) {
            const int pid = b * NC + kk;
            if (!(pend & (1u << r))) {
                u64* ap = &agg[((size_t)pid * 16 + g) * 2];
                union { f4 v; u64 u[2]; } pk;
                pk.u[0] = AT_LD(&ap[0]);
                pk.u[1] = AT_LD(&ap[1]);
                a += pk.v;
            } else {
                // emergency: recompute pred aggregate from x (64 KB).
                // Guarantees forward progress regardless of scheduling.
                const size_t pb = (size_t)pid * CH4 + g;
                f4 t = {0.f, 0.f, 0.f, 0.f};
                for (int tt = 0; tt < L; ++tt)
                    t += x[pb + (size_t)tt * ROW4];
                a += t;
            }
        }
    }
    part[s][g] = a;
    __syncthreads();
    // 2-level LDS reduce over the 16 kk-slots
    if (tid < 64) {
        const int u  = tid >> 4;   // 0..3
        const int gg = tid & 15;
        part2[u][gg] = part[4 * u + 0][gg] + part[4 * u + 1][gg]
                     + part[4 * u + 2][gg] + part[4 * u + 3][gg];
    }
    __syncthreads();
    if (tid < 16)
        off_lds[tid] = si + part2[0][tid] + part2[1][tid]
                          + part2[2][tid] + part2[3][tid];
    __syncthreads();

    // final: global offset + exclusive-within-chunk + running sums; stream stores
    f4 run = off_lds[g];
    if (s > 0) run += tot[s - 1][g];
    #pragma unroll
    for (int i = 0; i < VPT; ++i) {
        run += v[i];
        __builtin_nontemporal_store(run, &out[base + (size_t)i * ROW4]);
    }
}

// ================= fallback: previous verified 2-pass path =================
__global__ __launch_bounds__(256) void k_partial(const f4* __restrict__ x,
                                                 f4* __restrict__ out) {
    const int tid   = blockIdx.x * 256 + threadIdx.x;
    const int chunk = tid >> 4;
    const int g     = tid & 15;
    const size_t base = (size_t)chunk * CH4 + g;
    f4 s = {0.f, 0.f, 0.f, 0.f};
    #pragma unroll 8
    for (int t = 0; t < L; ++t)
        s += x[base + (size_t)t * ROW4];
    out[base] = s;
}

__global__ __launch_bounds__(256) void k_scan(const f4* __restrict__ s_init,
                                              f4* __restrict__ out) {
    const int tid = blockIdx.x * 256 + threadIdx.x;
    const int b   = tid >> 4;
    const int g   = tid & 15;
    f4 off = s_init[g];
    size_t idx = (size_t)b * NC * CH4 + g;
    #pragma unroll 4
    for (int kk = 0; kk < NC; ++kk, idx += CH4) {
        const f4 p = out[idx];
        out[idx] = off;
        off += p;
    }
}

__global__ __launch_bounds__(256) void k_write(const f4* __restrict__ x,
                                               f4* __restrict__ out) {
    const int tid   = blockIdx.x * 256 + threadIdx.x;
    const int chunk = tid >> 4;
    const int g     = tid & 15;
    const size_t base = (size_t)chunk * CH4 + g;
    f4 run = out[base];
    #pragma unroll 8
    for (int t = 0; t < L; ++t) {
        run += x[base + (size_t)t * ROW4];
        __builtin_nontemporal_store(run, &out[base + (size_t)t * ROW4]);
    }
}

extern "C" void kernel_launch(void* const* d_in, const int* in_sizes, int n_in,
                              void* d_out, int out_size, void* d_ws, size_t ws_size,
                              hipStream_t stream) {
    const f4* x      = (const f4*)d_in[0];
    const f4* s_init = (const f4*)d_in[1];
    f4* out          = (f4*)d_out;

    if (d_ws != nullptr && ws_size >= WS_NEED) {
        uint32_t* ws = (uint32_t*)d_ws;
        k_init   <<<dim3((NCHUNK + 255) / 256), dim3(256), 0, stream>>>(ws);
        k_onepass<<<dim3(NCHUNK), dim3(256), 0, stream>>>(x, s_init, out, ws);
    } else {
        dim3 blk(256);
        k_partial<<<dim3((B * NC * 16) / 256), blk, 0, stream>>>(x, out);
        k_scan   <<<dim3((B * 16) / 256),      blk, 0, stream>>>(s_init, out);
        k_write  <<<dim3((B * NC * 16) / 256), blk, 0, stream>>>(x, out);
    }
}